// Round 3
// baseline (254.203 us; speedup 1.0000x reference)
//
#include <hip/hip_runtime.h>
#include <hip/hip_bf16.h>
#include <math.h>

#define Bq 64
#define Tq 2048
#define Eq 256
#define Dq 256
#define Iq 256

using short8  = __attribute__((ext_vector_type(8))) short;
using floatx4 = __attribute__((ext_vector_type(4))) float;

__device__ __forceinline__ float fast_tanh(float x) {
    float e = __expf(2.0f * x);
    return 1.0f - 2.0f / (e + 1.0f);
}

__device__ __forceinline__ ushort f2bf(float x) {
    union { __hip_bfloat16 h; ushort u; } c;
    c.h = __float2bfloat16(x);
    return c.u;
}

// async 16B/lane global -> LDS (dest = wave-uniform base + lane*16)
__device__ __forceinline__ void async_load16(const void* g, void* l) {
    __builtin_amdgcn_global_load_lds(
        (const __attribute__((address_space(1))) void*)g,
        (__attribute__((address_space(3))) void*)l, 16, 0, 0);
}

// Fused prep:
//  blocks 0..31 : w1 fp32 -> bf16 in fragment-ordered layout
//                 w1sw[kc][i][8] (16B chunk = w1[i][kc*8 .. kc*8+7]), kc=blockIdx
//  blocks 32..95: dec_proj[b][i] = sum_d dec[b][d]*w2[i][d], b=blockIdx-32
__global__ __launch_bounds__(256) void prep_kernel(
    const float* __restrict__ w1, ushort* __restrict__ w1sw,
    const float* __restrict__ dec, const float* __restrict__ w2,
    float* __restrict__ dproj)
{
    if (blockIdx.x < 32) {
        const int kc = blockIdx.x;
        const int i  = threadIdx.x;
        const float* src = w1 + i * Eq + kc * 8;
        float4 f0 = *(const float4*)src;
        float4 f1 = *(const float4*)(src + 4);
        ushort u[8] = { f2bf(f0.x), f2bf(f0.y), f2bf(f0.z), f2bf(f0.w),
                        f2bf(f1.x), f2bf(f1.y), f2bf(f1.z), f2bf(f1.w) };
        *(short8*)&w1sw[(kc * 256 + i) * 8] = *(short8*)u;
    } else {
        const int b = blockIdx.x - 32;
        const int i = threadIdx.x;
        __shared__ float dls[Dq];
        dls[i] = dec[b * Dq + i];
        __syncthreads();
        const float* w2r = w2 + i * Dq;
        float acc = 0.f;
        #pragma unroll 8
        for (int d = 0; d < Dq; ++d) acc += dls[d] * w2r[d];
        dproj[b * Iq + i] = acc;
    }
}

// escore[b][t] = exp( sum_i v[i]*tanh((enc@w1^T)[t][i] + dproj[b][i]) )
// denom[b] += block partial sums (atomic).
// MFMA 16x16x32 bf16; block = 64 t x 256 i, 4 waves (wave w: i in [w*64,w*64+64)).
__global__ __launch_bounds__(256) void scores_mfma_kernel(
    const float*  __restrict__ enc,    // [B][T][E] fp32
    const ushort* __restrict__ w1sw,   // fragment-ordered bf16 [32 kc][256 i][8]
    const float*  __restrict__ v,      // [I]
    const float*  __restrict__ dproj,  // [B][I]
    float* __restrict__ escore,        // [B][T] (unnormalized exp)
    float* __restrict__ denom)         // [B]
{
    const int b   = blockIdx.y;
    const int t0  = blockIdx.x * 64;
    const int tid = threadIdx.x;
    const int w   = tid >> 6;
    const int l   = tid & 63;
    const int l15 = l & 15;
    const int lq  = l >> 4;

    __shared__ ushort As[64 * 72];   //  9.2 KB [t][e] bf16, pad 72
    __shared__ ushort Bs[16384];     // 32.8 KB fragment-ordered [8 kc][256 i][8]
    __shared__ float  vls[Iq], dls[Iq];

    vls[tid] = v[tid];
    dls[tid] = dproj[b * Iq + tid];

    floatx4 acc[4][4];
    #pragma unroll
    for (int mi = 0; mi < 4; ++mi)
        #pragma unroll
        for (int ni = 0; ni < 4; ++ni)
            acc[mi][ni] = (floatx4)0.f;

    const float* encB = enc + ((size_t)b * Tq + t0) * Eq;

    for (int k0 = 0; k0 < Eq; k0 += 64) {
        // async stage B: 32 KB contiguous chunk of w1sw, 8 insts/wave, no VGPR use
        const ushort* gb = w1sw + (size_t)(k0 >> 3) * 256 * 8;
        #pragma unroll
        for (int r = 0; r < 8; ++r) {
            const int qbase = r * 256 + w * 64;          // wave-uniform
            async_load16(gb + (qbase + l) * 8, Bs + qbase * 8);
        }
        // stage A via VGPR cvt: enc[t0+row][k0..k0+63] fp32 -> bf16
        #pragma unroll
        for (int r = 0; r < 4; ++r) {
            const int idx = tid + 256 * r;
            const int row = idx >> 4;
            const int c4  = (idx & 15) * 4;
            float4 f = *(const float4*)&encB[row * Eq + k0 + c4];
            ushort4 u;
            u.x = f2bf(f.x); u.y = f2bf(f.y); u.z = f2bf(f.z); u.w = f2bf(f.w);
            *(ushort4*)&As[row * 72 + c4] = u;
        }
        __syncthreads();
        #pragma unroll
        for (int ks = 0; ks < 2; ++ks) {
            const int kloc = ks * 32 + lq * 8;
            short8 af[4], bfv[4];
            #pragma unroll
            for (int mi = 0; mi < 4; ++mi)
                af[mi] = *(const short8*)&As[(mi * 16 + l15) * 72 + kloc];
            #pragma unroll
            for (int ni = 0; ni < 4; ++ni)
                bfv[ni] = *(const short8*)&Bs[((ks * 4 + lq) * 256 + w * 64 + ni * 16 + l15) * 8];
            #pragma unroll
            for (int mi = 0; mi < 4; ++mi)
                #pragma unroll
                for (int ni = 0; ni < 4; ++ni)
                    acc[mi][ni] = __builtin_amdgcn_mfma_f32_16x16x32_bf16(
                        af[mi], bfv[ni], acc[mi][ni], 0, 0, 0);
        }
        __syncthreads();
    }

    // epilogue: tanh + v-weight. C layout: col(i)=l15, row(t)=lq*4+reg.
    float part[4][4];
    #pragma unroll
    for (int mi = 0; mi < 4; ++mi)
        #pragma unroll
        for (int r = 0; r < 4; ++r) part[mi][r] = 0.f;

    #pragma unroll
    for (int ni = 0; ni < 4; ++ni) {
        const int i   = w * 64 + ni * 16 + l15;
        const float vi = vls[i];
        const float dp = dls[i];
        #pragma unroll
        for (int mi = 0; mi < 4; ++mi)
            #pragma unroll
            for (int r = 0; r < 4; ++r)
                part[mi][r] += vi * fast_tanh(acc[mi][ni][r] + dp);
    }

    // LDS transpose-reduce (reuse Bs; safe: trailing barrier passed).
    // red2[w][t_local][l15], row stride 20 floats (80 B, 16B-aligned, conflict-free)
    float* red2 = (float*)Bs;    // needs 4*64*20*4 = 20.5 KB <= 32.8 KB
    #pragma unroll
    for (int mi = 0; mi < 4; ++mi)
        #pragma unroll
        for (int r = 0; r < 4; ++r)
            red2[(w * 64 + mi * 16 + lq * 4 + r) * 20 + l15] = part[mi][r];
    __syncthreads();

    if (tid < 64) {
        float s = 0.f;
        #pragma unroll
        for (int ww = 0; ww < 4; ++ww) {
            const float* rp = red2 + (ww * 64 + tid) * 20;
            float4 q0 = *(const float4*)(rp + 0);
            float4 q1 = *(const float4*)(rp + 4);
            float4 q2 = *(const float4*)(rp + 8);
            float4 q3 = *(const float4*)(rp + 12);
            s += (q0.x + q0.y + q0.z + q0.w) + (q1.x + q1.y + q1.z + q1.w)
               + (q2.x + q2.y + q2.z + q2.w) + (q3.x + q3.y + q3.z + q3.w);
        }
        const float es = __expf(s);   // |s| <= 8 -> no overflow; softmax w/o max-sub
        escore[(size_t)b * Tq + t0 + tid] = es;
        float tot = es;
        tot += __shfl_xor(tot, 1);  tot += __shfl_xor(tot, 2);
        tot += __shfl_xor(tot, 4);  tot += __shfl_xor(tot, 8);
        tot += __shfl_xor(tot, 16); tot += __shfl_xor(tot, 32);
        if (tid == 0) atomicAdd(&denom[b], tot);
    }
}

// probs = escore/denom (written out); ctx[b][e] += sum_t probs*enc (atomic)
__global__ __launch_bounds__(256) void context_kernel(
    const float* __restrict__ enc, const float* __restrict__ escore,
    const float* __restrict__ denom,
    float* __restrict__ probs, float* __restrict__ ctx)
{
    const int b   = blockIdx.y;
    const int t0  = blockIdx.x * 256;
    const int tid = threadIdx.x;
    const int tg  = tid >> 6;
    const int e4  = (tid & 63) * 4;

    __shared__ float pv[256];
    __shared__ float red[4][256];

    const float inv = 1.0f / denom[b];
    const float p = escore[(size_t)b * Tq + t0 + tid] * inv;
    pv[tid] = p;
    probs[(size_t)b * Tq + t0 + tid] = p;
    __syncthreads();

    const float* encB = enc + ((size_t)b * Tq + t0) * Eq;
    float4 a = {0.f, 0.f, 0.f, 0.f};
    #pragma unroll 4
    for (int tt = 0; tt < 64; ++tt) {
        const int t = tt * 4 + tg;               // wave-uniform row
        const float pt = pv[t];
        float4 ev = *(const float4*)&encB[t * Eq + e4];
        a.x += pt * ev.x; a.y += pt * ev.y; a.z += pt * ev.z; a.w += pt * ev.w;
    }
    *(float4*)&red[tg][e4] = a;
    __syncthreads();
    if (tg == 0) {
        float4 a0 = *(const float4*)&red[0][e4];
        float4 a1 = *(const float4*)&red[1][e4];
        float4 a2 = *(const float4*)&red[2][e4];
        float4 a3 = *(const float4*)&red[3][e4];
        float* c = ctx + b * Eq + e4;
        atomicAdd(c + 0, a0.x + a1.x + a2.x + a3.x);
        atomicAdd(c + 1, a0.y + a1.y + a2.y + a3.y);
        atomicAdd(c + 2, a0.z + a1.z + a2.z + a3.z);
        atomicAdd(c + 3, a0.w + a1.w + a2.w + a3.w);
    }
}

extern "C" void kernel_launch(void* const* d_in, const int* in_sizes, int n_in,
                              void* d_out, int out_size, void* d_ws, size_t ws_size,
                              hipStream_t stream) {
    const float* enc = (const float*)d_in[0];  // [64][2048][256]
    const float* dec = (const float*)d_in[1];  // [64][256]
    const float* w1  = (const float*)d_in[2];  // [256][256]
    const float* w2  = (const float*)d_in[3];  // [256][256]
    const float* v   = (const float*)d_in[4];  // [1][256]

    float* out   = (float*)d_out;
    float* ctx   = out;                 // [64][256]  output 0
    float* probs = out + Bq * Eq;       // [64][2048] output 1 (escore scratch first)

    char* ws = (char*)d_ws;
    float*  dproj = (float*)ws;                          // 256 KB
    ushort* w1sw  = (ushort*)(ws + 262144);              // 128 KB
    float*  denom = (float*)(ws + 262144 + 131072);      // 256 B

    hipMemsetAsync(ctx, 0, Bq * Eq * sizeof(float), stream);
    hipMemsetAsync(denom, 0, Bq * sizeof(float), stream);

    prep_kernel<<<dim3(96), dim3(256), 0, stream>>>(w1, w1sw, dec, w2, dproj);
    scores_mfma_kernel<<<dim3(Tq / 64, Bq), dim3(256), 0, stream>>>(
        enc, w1sw, v, dproj, probs, denom);
    context_kernel<<<dim3(Tq / 256, Bq), dim3(256), 0, stream>>>(
        enc, probs, denom, probs, ctx);
}

// Round 4
// 233.549 us; speedup vs baseline: 1.0884x; 1.0884x over previous
//
#include <hip/hip_runtime.h>
#include <hip/hip_bf16.h>
#include <math.h>

#define Bq 64
#define Tq 2048
#define Eq 256
#define Dq 256
#define Iq 256

using short8  = __attribute__((ext_vector_type(8))) short;
using floatx4 = __attribute__((ext_vector_type(4))) float;

__device__ __forceinline__ float fast_tanh(float x) {
    float e = __expf(2.0f * x);
    return 1.0f - 2.0f / (e + 1.0f);
}

__device__ __forceinline__ ushort f2bf(float x) {
    union { __hip_bfloat16 h; ushort u; } c;
    c.h = __float2bfloat16(x);
    return c.u;
}

// async 16B/lane global -> LDS (dest = wave-uniform base + lane*16)
__device__ __forceinline__ void async_load16(const void* g, void* l) {
    __builtin_amdgcn_global_load_lds(
        (const __attribute__((address_space(1))) void*)g,
        (__attribute__((address_space(3))) void*)l, 16, 0, 0);
}

// Fused prep:
//  blocks 0..31 : w1 fp32 -> bf16 fragment-ordered: w1sw[kc][i][8], kc=k/8
//  blocks 32..95: dec_proj[b][i] = sum_d dec[b][d]*w2[i][d], b=blockIdx-32
__global__ __launch_bounds__(256) void prep_kernel(
    const float* __restrict__ w1, ushort* __restrict__ w1sw,
    const float* __restrict__ dec, const float* __restrict__ w2,
    float* __restrict__ dproj)
{
    if (blockIdx.x < 32) {
        const int kc = blockIdx.x;
        const int i  = threadIdx.x;
        const float* src = w1 + i * Eq + kc * 8;
        float4 f0 = *(const float4*)src;
        float4 f1 = *(const float4*)(src + 4);
        ushort u[8] = { f2bf(f0.x), f2bf(f0.y), f2bf(f0.z), f2bf(f0.w),
                        f2bf(f1.x), f2bf(f1.y), f2bf(f1.z), f2bf(f1.w) };
        *(short8*)&w1sw[(kc * 256 + i) * 8] = *(short8*)u;
    } else {
        const int b = blockIdx.x - 32;
        const int i = threadIdx.x;
        __shared__ float dls[Dq];
        dls[i] = dec[b * Dq + i];
        __syncthreads();
        const float* w2r = w2 + i * Dq;
        float acc = 0.f;
        #pragma unroll 8
        for (int d = 0; d < Dq; ++d) acc += dls[d] * w2r[d];
        dproj[b * Iq + i] = acc;
    }
}

// Fused scores + unnormalized-context.
//  escore[b][t]          = exp( sum_i v[i]*tanh((enc@w1^T)[t][i] + dproj[b][i]) )
//  denomp[chunk][b]      = sum over this block's 64 t of escore     (no atomics)
//  ctxp[chunk][b][e]     = sum over this block's 64 t of escore*enc (no atomics)
// MFMA 16x16x32 bf16; block = 64 t x 256 i, 4 waves.
__global__ __launch_bounds__(256) void scores_ctx_kernel(
    const float*  __restrict__ enc,    // [B][T][E] fp32
    const ushort* __restrict__ w1sw,   // fragment-ordered bf16 [32 kc][256 i][8]
    const float*  __restrict__ v,      // [I]
    const float*  __restrict__ dproj,  // [B][I]
    float* __restrict__ escore,        // [B][T] unnormalized exp (probs buffer)
    float* __restrict__ ctxp,          // [32][B][E] context partials
    float* __restrict__ denomp)        // [32][B]
{
    const int b   = blockIdx.y;
    const int bx  = blockIdx.x;
    const int t0  = bx * 64;
    const int tid = threadIdx.x;
    const int w   = tid >> 6;
    const int l   = tid & 63;
    const int l15 = l & 15;
    const int lq  = l >> 4;

    __shared__ ushort As[64 * 72];   //  9.2 KB [t][e] bf16, pad 72
    __shared__ ushort Bs[16384];     // 32.8 KB fragment-ordered [8 kc][256 i][8]
    __shared__ float  vls[Iq], dls[Iq];
    __shared__ float  pv[64];

    vls[tid] = v[tid];
    dls[tid] = dproj[b * Iq + tid];

    floatx4 acc[4][4];
    #pragma unroll
    for (int mi = 0; mi < 4; ++mi)
        #pragma unroll
        for (int ni = 0; ni < 4; ++ni)
            acc[mi][ni] = (floatx4)0.f;

    const float* encB = enc + ((size_t)b * Tq + t0) * Eq;

    for (int k0 = 0; k0 < Eq; k0 += 64) {
        // async stage B: 32 KB contiguous chunk of w1sw
        const ushort* gb = w1sw + (size_t)(k0 >> 3) * 256 * 8;
        #pragma unroll
        for (int r = 0; r < 8; ++r) {
            const int qbase = r * 256 + w * 64;          // wave-uniform
            async_load16(gb + (qbase + l) * 8, Bs + qbase * 8);
        }
        // stage A: enc[t0+row][k0..k0+63] fp32 -> bf16
        #pragma unroll
        for (int r = 0; r < 4; ++r) {
            const int idx = tid + 256 * r;
            const int row = idx >> 4;
            const int c4  = (idx & 15) * 4;
            float4 f = *(const float4*)&encB[row * Eq + k0 + c4];
            ushort4 u;
            u.x = f2bf(f.x); u.y = f2bf(f.y); u.z = f2bf(f.z); u.w = f2bf(f.w);
            *(ushort4*)&As[row * 72 + c4] = u;
        }
        __syncthreads();
        #pragma unroll
        for (int ks = 0; ks < 2; ++ks) {
            const int kloc = ks * 32 + lq * 8;
            short8 af[4], bfv[4];
            #pragma unroll
            for (int mi = 0; mi < 4; ++mi)
                af[mi] = *(const short8*)&As[(mi * 16 + l15) * 72 + kloc];
            #pragma unroll
            for (int ni = 0; ni < 4; ++ni)
                bfv[ni] = *(const short8*)&Bs[((ks * 4 + lq) * 256 + w * 64 + ni * 16 + l15) * 8];
            #pragma unroll
            for (int mi = 0; mi < 4; ++mi)
                #pragma unroll
                for (int ni = 0; ni < 4; ++ni)
                    acc[mi][ni] = __builtin_amdgcn_mfma_f32_16x16x32_bf16(
                        af[mi], bfv[ni], acc[mi][ni], 0, 0, 0);
        }
        __syncthreads();
    }

    // epilogue: tanh + v-weight. C layout: col(i)=l15, row(t)=lq*4+reg.
    float part[4][4];
    #pragma unroll
    for (int mi = 0; mi < 4; ++mi)
        #pragma unroll
        for (int r = 0; r < 4; ++r) part[mi][r] = 0.f;

    #pragma unroll
    for (int ni = 0; ni < 4; ++ni) {
        const int i   = w * 64 + ni * 16 + l15;
        const float vi = vls[i];
        const float dp = dls[i];
        #pragma unroll
        for (int mi = 0; mi < 4; ++mi)
            #pragma unroll
            for (int r = 0; r < 4; ++r)
                part[mi][r] += vi * fast_tanh(acc[mi][ni][r] + dp);
    }

    // LDS transpose-reduce (reuse Bs). red2[w][t_local][l15], stride 20 floats.
    float* red2 = (float*)Bs;    // 4*64*20*4 = 20.5 KB <= 32.8 KB
    #pragma unroll
    for (int mi = 0; mi < 4; ++mi)
        #pragma unroll
        for (int r = 0; r < 4; ++r)
            red2[(w * 64 + mi * 16 + lq * 4 + r) * 20 + l15] = part[mi][r];
    __syncthreads();

    if (tid < 64) {
        float s = 0.f;
        #pragma unroll
        for (int ww = 0; ww < 4; ++ww) {
            const float* rp = red2 + (ww * 64 + tid) * 20;
            float4 q0 = *(const float4*)(rp + 0);
            float4 q1 = *(const float4*)(rp + 4);
            float4 q2 = *(const float4*)(rp + 8);
            float4 q3 = *(const float4*)(rp + 12);
            s += (q0.x + q0.y + q0.z + q0.w) + (q1.x + q1.y + q1.z + q1.w)
               + (q2.x + q2.y + q2.z + q2.w) + (q3.x + q3.y + q3.z + q3.w);
        }
        const float es = __expf(s);   // |s| <= ~16 -> safe in fp32 w/o max-sub
        pv[tid] = es;
        escore[(size_t)b * Tq + t0 + tid] = es;
        float tot = es;
        tot += __shfl_xor(tot, 1);  tot += __shfl_xor(tot, 2);
        tot += __shfl_xor(tot, 4);  tot += __shfl_xor(tot, 8);
        tot += __shfl_xor(tot, 16); tot += __shfl_xor(tot, 32);
        if (tid == 0) denomp[bx * Bq + b] = tot;
    }
    __syncthreads();

    // fused context partial: ctxp[bx][b][e] = sum_t pv[t]*enc[t][e]
    // enc tile (64 KB) was just read -> L2-resident re-read.
    const int tg = tid >> 6;            // t quarter 0..3
    const int el = (tid & 63) * 4;      // e in float4 units
    float4 a = {0.f, 0.f, 0.f, 0.f};
    #pragma unroll 4
    for (int tt = 0; tt < 16; ++tt) {
        const int t = tg * 16 + tt;     // wave-uniform
        const float pt = pv[t];
        float4 ev = *(const float4*)&encB[t * Eq + el];
        a.x += pt * ev.x; a.y += pt * ev.y; a.z += pt * ev.z; a.w += pt * ev.w;
    }
    float* redf = (float*)As;           // 4 KB <= 9.2 KB, As no longer needed
    *(float4*)&redf[tg * 256 + el] = a;
    __syncthreads();
    if (tg == 0) {
        float4 a0 = *(const float4*)&redf[0 * 256 + el];
        float4 a1 = *(const float4*)&redf[1 * 256 + el];
        float4 a2 = *(const float4*)&redf[2 * 256 + el];
        float4 a3 = *(const float4*)&redf[3 * 256 + el];
        float4 o;
        o.x = a0.x + a1.x + a2.x + a3.x;
        o.y = a0.y + a1.y + a2.y + a3.y;
        o.z = a0.z + a1.z + a2.z + a3.z;
        o.w = a0.w + a1.w + a2.w + a3.w;
        *(float4*)&ctxp[((size_t)bx * Bq + b) * Eq + el] = o;
    }
}

// One block per b: denom = sum_c denomp[c][b]; probs *= 1/denom (in place);
// ctx[b][e] = (sum_c ctxp[c][b][e]) / denom.
__global__ __launch_bounds__(256) void finalize_kernel(
    const float* __restrict__ ctxp, const float* __restrict__ denomp,
    float* __restrict__ probs, float* __restrict__ ctx)
{
    const int b   = blockIdx.x;
    const int tid = threadIdx.x;

    float d = denomp[(tid & 31) * Bq + b];
    d += __shfl_xor(d, 1);  d += __shfl_xor(d, 2);  d += __shfl_xor(d, 4);
    d += __shfl_xor(d, 8);  d += __shfl_xor(d, 16);
    const float inv = 1.0f / d;

    float* prow = probs + (size_t)b * Tq + tid * 8;
    float4 p0 = *(const float4*)(prow + 0);
    float4 p1 = *(const float4*)(prow + 4);
    p0.x *= inv; p0.y *= inv; p0.z *= inv; p0.w *= inv;
    p1.x *= inv; p1.y *= inv; p1.z *= inv; p1.w *= inv;
    *(float4*)(prow + 0) = p0;
    *(float4*)(prow + 4) = p1;

    float s = 0.f;
    #pragma unroll 8
    for (int c = 0; c < 32; ++c)
        s += ctxp[((size_t)c * Bq + b) * Eq + tid];
    ctx[b * Eq + tid] = s * inv;
}

extern "C" void kernel_launch(void* const* d_in, const int* in_sizes, int n_in,
                              void* d_out, int out_size, void* d_ws, size_t ws_size,
                              hipStream_t stream) {
    const float* enc = (const float*)d_in[0];  // [64][2048][256]
    const float* dec = (const float*)d_in[1];  // [64][256]
    const float* w1  = (const float*)d_in[2];  // [256][256]
    const float* w2  = (const float*)d_in[3];  // [256][256]
    const float* v   = (const float*)d_in[4];  // [1][256]

    float* out   = (float*)d_out;
    float* ctx   = out;                 // [64][256]  output 0
    float* probs = out + Bq * Eq;       // [64][2048] output 1 (escore first)

    char* ws = (char*)d_ws;
    float*  ctxp   = (float*)ws;                        // 2 MB  [32][64][256]
    float*  denomp = (float*)(ws + (32*Bq*Eq)*4);       // 8 KB  [32][64]
    float*  dproj  = (float*)(ws + (32*Bq*Eq)*4 + 32*Bq*4);          // 64 KB
    ushort* w1sw   = (ushort*)(ws + (32*Bq*Eq)*4 + 32*Bq*4 + Bq*Iq*4); // 128 KB

    // all ws buffers are fully overwritten each call -> no memsets needed
    prep_kernel<<<dim3(96), dim3(256), 0, stream>>>(w1, w1sw, dec, w2, dproj);
    scores_ctx_kernel<<<dim3(Tq / 64, Bq), dim3(256), 0, stream>>>(
        enc, w1sw, v, dproj, probs, ctxp, denomp);
    finalize_kernel<<<dim3(Bq), dim3(256), 0, stream>>>(ctxp, denomp, probs, ctx);
}